// Round 2
// baseline (615.190 us; speedup 1.0000x reference)
//
#include <hip/hip_runtime.h>
#include <math.h>

// DigitCaps dynamic routing, fp32, single-W-pass fused logit+softmax+s.
#define IN_CAPS 1152
#define OUT_CAPS 10
#define OUT_DIM 16
#define IN_DIM 8
#define BATCH 512
#define JD (OUT_CAPS * OUT_DIM)   // 160

#define GB 16                 // batches per block (8 waves x 2 b-lanes)
#define ICH 48                // input caps per block (12 slabs of 4)
#define NBB (BATCH / GB)      // 32
#define NIC (IN_CAPS / ICH)   // 24
#define IPT (ICH / 4)         // 12
#define ATH 512

// Workspace: S_part[NIC][BATCH][JD] fp32 (7.9 MB), then V[BATCH][JD].

// Lane layout: dgrp = lane&7 (owns d0=2*dgrp, d0+1 for ALL j),
//              islot = (lane>>3)&3 (4 i's per slab), bsl = lane>>5 (2 b's).
// MODE 0: c = 0.1 uniform (softmax of zero logits). MODE 1: logits from V.
template<int MODE>
__global__ __launch_bounds__(ATH) void accum_kernel(
    const float* __restrict__ X, const float* __restrict__ W,
    const float* __restrict__ V, float* __restrict__ S_part)
{
    __shared__ float V_lds[GB][JD];

    const int tid = threadIdx.x;
    const int bid = blockIdx.x;
    const int bcb = bid / NIC;
    const int icb = bid % NIC;

    if (MODE != 0) {
        for (int t = tid; t < GB * JD; t += ATH)
            V_lds[t / JD][t % JD] = V[(bcb * GB + t / JD) * JD + t % JD];
    }
    __syncthreads();

    const int lane  = tid & 63;
    const int wave  = tid >> 6;
    const int dgrp  = lane & 7;
    const int islot = (lane >> 3) & 3;
    const int bsl   = lane >> 5;
    const int wb    = wave * 2 + bsl;      // 0..15
    const int b     = bcb * GB + wb;
    const int d0    = dgrp * 2;

    const float4* __restrict__ X4 = (const float4*)X;
    const float4* __restrict__ W4 = (const float4*)W;

    float2 s_acc[OUT_CAPS];
#pragma unroll
    for (int j = 0; j < OUT_CAPS; j++) s_acc[j] = make_float2(0.f, 0.f);

    for (int t = 0; t < IPT; ++t) {
        __syncthreads();  // rally waves onto the same 20 KB W slab (L1 reuse)
        const int i = icb * ICH + t * 4 + islot;
        const float4 xv0 = X4[(b * IN_CAPS + i) * 2];
        const float4 xv1 = X4[(b * IN_CAPS + i) * 2 + 1];
        const int wbase = i * 320 + dgrp * 4;   // float4 units

        float2 u[OUT_CAPS];
        float  L[OUT_CAPS];
#pragma unroll
        for (int j = 0; j < OUT_CAPS; j++) {
            const float4 w0 = W4[wbase + j * 32 + 0];   // row d0, e0..3
            const float4 w1 = W4[wbase + j * 32 + 1];   // row d0, e4..7
            const float4 w2 = W4[wbase + j * 32 + 2];   // row d0+1
            const float4 w3 = W4[wbase + j * 32 + 3];
            const float u0 = w0.x*xv0.x + w0.y*xv0.y + w0.z*xv0.z + w0.w*xv0.w
                           + w1.x*xv1.x + w1.y*xv1.y + w1.z*xv1.z + w1.w*xv1.w;
            const float u1 = w2.x*xv0.x + w2.y*xv0.y + w2.z*xv0.z + w2.w*xv0.w
                           + w3.x*xv1.x + w3.y*xv1.y + w3.z*xv1.z + w3.w*xv1.w;
            u[j] = make_float2(u0, u1);
            if (MODE != 0) {
                const float2 vv = *(const float2*)&V_lds[wb][j * 16 + d0];
                L[j] = u0 * vv.x + u1 * vv.y;
            }
        }

        float c[OUT_CAPS];
        if (MODE != 0) {
            // sum partial logits over the 8 d-pair lanes
#pragma unroll
            for (int j = 0; j < OUT_CAPS; j++) {
                L[j] += __shfl_xor(L[j], 1);
                L[j] += __shfl_xor(L[j], 2);
                L[j] += __shfl_xor(L[j], 4);
            }
            float m = L[0];
#pragma unroll
            for (int j = 1; j < OUT_CAPS; j++) m = fmaxf(m, L[j]);
            float Z = 0.f;
#pragma unroll
            for (int j = 0; j < OUT_CAPS; j++) { c[j] = __expf(L[j] - m); Z += c[j]; }
            const float rz = 1.f / Z;
#pragma unroll
            for (int j = 0; j < OUT_CAPS; j++) c[j] *= rz;
        } else {
#pragma unroll
            for (int j = 0; j < OUT_CAPS; j++) c[j] = 0.1f;
        }

#pragma unroll
        for (int j = 0; j < OUT_CAPS; j++) {
            s_acc[j].x += c[j] * u[j].x;
            s_acc[j].y += c[j] * u[j].y;
        }
    }

    // reduce s over the 4 islot lanes (bits 3,4)
#pragma unroll
    for (int j = 0; j < OUT_CAPS; j++) {
        s_acc[j].x += __shfl_xor(s_acc[j].x, 8);
        s_acc[j].x += __shfl_xor(s_acc[j].x, 16);
        s_acc[j].y += __shfl_xor(s_acc[j].y, 8);
        s_acc[j].y += __shfl_xor(s_acc[j].y, 16);
    }
    if (islot == 0) {
        float2* Sp = (float2*)&S_part[((long)icb * BATCH + b) * JD];
#pragma unroll
        for (int j = 0; j < OUT_CAPS; j++)
            Sp[j * 8 + dgrp] = s_acc[j];   // (j*16 + d0)/2
    }
}

// mode: 0 -> V = v (iter0), 1 -> V += v (iter1), 2 -> out = v (final)
__global__ __launch_bounds__(256) void squash_kernel(
    const float* __restrict__ S_part, float* __restrict__ V,
    float* __restrict__ out, int mode)
{
    const int t = blockIdx.x * 256 + threadIdx.x;  // 0 .. BATCH*JD-1
    float s = 0.f;
#pragma unroll
    for (int ic = 0; ic < NIC; ic++)
        s += S_part[(long)ic * BATCH * JD + t];
    float sq = s * s;
    sq += __shfl_xor(sq, 1);
    sq += __shfl_xor(sq, 2);
    sq += __shfl_xor(sq, 4);
    sq += __shfl_xor(sq, 8);
    const float v = s * sq / ((1.f + sq) * sqrtf(sq + 1e-8f));
    if (mode == 0)      V[t] = v;
    else if (mode == 1) V[t] += v;
    else                out[t] = v;
}

extern "C" void kernel_launch(void* const* d_in, const int* in_sizes, int n_in,
                              void* d_out, int out_size, void* d_ws, size_t ws_size,
                              hipStream_t stream)
{
    const float* X = (const float*)d_in[0];   // [512][1152][8]
    const float* W = (const float*)d_in[1];   // [1152][10][16][8]
    float* out = (float*)d_out;               // [512][10][16]

    float* S_part = (float*)d_ws;
    float* V      = S_part + (long)NIC * BATCH * JD;

    const dim3 ag(NBB * NIC), ab(ATH);        // 768 blocks x 512
    const dim3 sg(BATCH * JD / 256), sb(256);

    accum_kernel<0><<<ag, ab, 0, stream>>>(X, W, V, S_part);
    squash_kernel<<<sg, sb, 0, stream>>>(S_part, V, out, 0);   // V = v0
    accum_kernel<1><<<ag, ab, 0, stream>>>(X, W, V, S_part);
    squash_kernel<<<sg, sb, 0, stream>>>(S_part, V, out, 1);   // V += v1
    accum_kernel<1><<<ag, ab, 0, stream>>>(X, W, V, S_part);
    squash_kernel<<<sg, sb, 0, stream>>>(S_part, V, out, 2);   // out = v2
}

// Round 3
// 330.744 us; speedup vs baseline: 1.8600x; 1.8600x over previous
//
#include <hip/hip_runtime.h>
#include <math.h>

// DigitCaps dynamic routing via MFMA u_hat + fully fused in-register routing.
#define J 10
#define BT 16          // batch tile (MFMA N)
#define NBT 32         // BATCH/BT
#define NIC 18         // i-chunks
#define ICB 64         // IN_CAPS/NIC
#define IPW 8          // i per wave (8 waves/block)
#define JD 160
#define BATCH 512
#define IN_CAPS 1152

typedef __attribute__((ext_vector_type(8))) short short8;
typedef __attribute__((ext_vector_type(4))) float f32x4;

__device__ inline short f2bf(float f) {
    union { float f; unsigned u; } v; v.f = f;
    return (short)((v.u + 0x7FFFu + ((v.u >> 16) & 1u)) >> 16);  // RNE
}
__device__ inline short8 cvt8(float4 a, float4 b) {
    short8 o;
    o[0] = f2bf(a.x); o[1] = f2bf(a.y); o[2] = f2bf(a.z); o[3] = f2bf(a.w);
    o[4] = f2bf(b.x); o[5] = f2bf(b.y); o[6] = f2bf(b.z); o[7] = f2bf(b.w);
    return o;
}

// W fp32 -> bf16 (same [i][j][d][e] layout), and zero pad-buffer.
__global__ __launch_bounds__(256) void convert_kernel(
    const float* __restrict__ W, short* __restrict__ Wb, short* __restrict__ zb)
{
    const int t = blockIdx.x * 256 + threadIdx.x;   // 184320 threads exactly
    const float4* src = (const float4*)W + (size_t)t * 2;
    *(short8*)(Wb + (size_t)t * 8) = cvt8(src[0], src[1]);
    if (blockIdx.x == 0 && threadIdx.x < 32) zb[threadIdx.x] = 0;
}

// MODE 0: c = 0.1 (pure GEMM, K=32 = 4 i x 8 e).  MODE 1: logits from V, softmax, s.
// MFMA orientation: A = W (M rows = 16 d of one j), B = X (N cols = 16 b), K = e.
// C layout: col = lane&15 = b, row = (lane>>4)*4 + reg = d.
template<int MODE>
__global__ __launch_bounds__(512, 2) void route_kernel(
    const float* __restrict__ X, const short* __restrict__ Wb,
    const short* __restrict__ zb, const float* __restrict__ V,
    float* __restrict__ S_part)
{
    __shared__ float s_lds[BT][JD + 1];
    const int tid   = threadIdx.x;
    const int lane  = tid & 63, wave = tid >> 6;
    const int btile = blockIdx.x / NIC, icb = blockIdx.x % NIC;
    const int bcol  = lane & 15, kg = lane >> 4;

    for (int t = tid; t < BT * (JD + 1); t += 512) (&s_lds[0][0])[t] = 0.f;
    __syncthreads();

    float s_acc[J][4];
#pragma unroll
    for (int j = 0; j < J; ++j)
#pragma unroll
        for (int r = 0; r < 4; ++r) s_acc[j][r] = 0.f;

    const int i0w = icb * ICB + wave * IPW;

    if (MODE == 0) {
        f32x4 acc[J];
#pragma unroll
        for (int j = 0; j < J; ++j) acc[j] = (f32x4)(0.f);
#pragma unroll
        for (int st = 0; st < IPW / 4; ++st) {
            const int ia = i0w + st * 4 + kg;            // lane's i (k-group)
            const float4* xp = (const float4*)(X + ((size_t)(btile * BT + bcol) * IN_CAPS + ia) * 8);
            const short8 bfr = cvt8(xp[0], xp[1]);       // B = x[b, i(kg), e]
#pragma unroll
            for (int j = 0; j < J; ++j) {
                const short8 afr = *(const short8*)(Wb + ((size_t)ia * JD + j * 16 + bcol) * 8);
                acc[j] = __builtin_amdgcn_mfma_f32_16x16x32_bf16(afr, bfr, acc[j], 0, 0, 0);
            }
        }
#pragma unroll
        for (int j = 0; j < J; ++j)
#pragma unroll
            for (int r = 0; r < 4; ++r) s_acc[j][r] = 0.1f * acc[j][r];
    } else {
        float Vr[J][4];
#pragma unroll
        for (int j = 0; j < J; ++j)
#pragma unroll
            for (int r = 0; r < 4; ++r)
                Vr[j][r] = V[(size_t)(btile * BT + bcol) * JD + j * 16 + kg * 4 + r];

        // zero-stride trick: lanes >=16 read the 64B zero buffer (k=8..31 pad).
        const bool act = (lane < 16);
        const float* xbase = act ? (X + (size_t)(btile * BT + bcol) * IN_CAPS * 8)
                                 : (const float*)zb;
        const int xis = act ? 8 : 0;
        const short* wb0 = act ? (Wb + (size_t)bcol * 8) : zb;
        const int wis = act ? (JD * 8) : 0;
        const int wjs = act ? 128 : 0;

        for (int ii = 0; ii < IPW; ++ii) {
            const int i = i0w + ii;
            const float4* xp = (const float4*)(xbase + (size_t)i * xis);
            const short8 bfr = cvt8(xp[0], xp[1]);
            const short* wp = wb0 + (size_t)i * wis;
            f32x4 u[J];
#pragma unroll
            for (int j = 0; j < J; ++j) {
                const short8 afr = *(const short8*)(wp + j * wjs);
                u[j] = __builtin_amdgcn_mfma_f32_16x16x32_bf16(afr, bfr, (f32x4)(0.f), 0, 0, 0);
            }
            // logits L[j] = sum_d u[d]*V[d]: 4 in-register + 2-step lane reduce
            float L[J];
#pragma unroll
            for (int j = 0; j < J; ++j) {
                float l = u[j][0] * Vr[j][0] + u[j][1] * Vr[j][1]
                        + u[j][2] * Vr[j][2] + u[j][3] * Vr[j][3];
                l += __shfl_xor(l, 16);
                l += __shfl_xor(l, 32);
                L[j] = l;
            }
            // softmax over j (logits bounded ~|L|<5: no max-sub needed)
            float e[J], Z = 0.f;
#pragma unroll
            for (int j = 0; j < J; ++j) { e[j] = __expf(L[j]); Z += e[j]; }
            const float rz = 1.0f / Z;
#pragma unroll
            for (int j = 0; j < J; ++j) {
                const float c = e[j] * rz;
#pragma unroll
                for (int r = 0; r < 4; ++r) s_acc[j][r] += c * u[j][r];
            }
        }
    }

    // cross-wave reduce: each lane owns distinct (b=bcol, d=kg*4+r) per j
#pragma unroll
    for (int j = 0; j < J; ++j)
#pragma unroll
        for (int r = 0; r < 4; ++r)
            atomicAdd(&s_lds[bcol][j * 16 + kg * 4 + r], s_acc[j][r]);
    __syncthreads();

    for (int t = tid; t < BT * JD; t += 512) {
        const int b = t / JD, p = t % JD;
        S_part[((size_t)icb * BATCH + btile * BT + b) * JD + p] = s_lds[b][p];
    }
}

// mode: 0 -> V = v, 1 -> V += v, 2 -> out = v
__global__ __launch_bounds__(256) void squash_kernel(
    const float* __restrict__ S_part, float* __restrict__ V,
    float* __restrict__ out, int mode)
{
    const int t = blockIdx.x * 256 + threadIdx.x;  // BATCH*JD threads
    float s = 0.f;
#pragma unroll
    for (int ic = 0; ic < NIC; ic++)
        s += S_part[(size_t)ic * BATCH * JD + t];
    float sq = s * s;
    sq += __shfl_xor(sq, 1);
    sq += __shfl_xor(sq, 2);
    sq += __shfl_xor(sq, 4);
    sq += __shfl_xor(sq, 8);
    const float v = s * sq / ((1.f + sq) * sqrtf(sq + 1e-8f));
    if (mode == 0)      V[t] = v;
    else if (mode == 1) V[t] += v;
    else                out[t] = v;
}

extern "C" void kernel_launch(void* const* d_in, const int* in_sizes, int n_in,
                              void* d_out, int out_size, void* d_ws, size_t ws_size,
                              hipStream_t stream)
{
    const float* X = (const float*)d_in[0];   // [512][1152][8]
    const float* W = (const float*)d_in[1];   // [1152][10][16][8]
    float* out = (float*)d_out;               // [512][10][16]

    // ws: S_part[18][512][160] f32 | V[512][160] f32 | Wb bf16 | zb (64B zeros)
    float* S_part = (float*)d_ws;
    float* V      = S_part + (size_t)NIC * BATCH * JD;
    short* Wb     = (short*)(V + (size_t)BATCH * JD);
    short* zb     = Wb + (size_t)IN_CAPS * JD * 8;

    const dim3 rg(NBT * NIC), rb(512);        // 576 blocks x 8 waves
    const dim3 sg(BATCH * JD / 256), sb(256); // 320 blocks
    convert_kernel<<<dim3(IN_CAPS * JD * 8 / 2048), dim3(256), 0, stream>>>(W, Wb, zb);

    route_kernel<0><<<rg, rb, 0, stream>>>(X, Wb, zb, V, S_part);
    squash_kernel<<<sg, sb, 0, stream>>>(S_part, V, out, 0);   // V = v0
    route_kernel<1><<<rg, rb, 0, stream>>>(X, Wb, zb, V, S_part);
    squash_kernel<<<sg, sb, 0, stream>>>(S_part, V, out, 1);   // V += v1
    route_kernel<1><<<rg, rb, 0, stream>>>(X, Wb, zb, V, S_part);
    squash_kernel<<<sg, sb, 0, stream>>>(S_part, V, out, 2);   // out = v2
}

// Round 4
// 317.794 us; speedup vs baseline: 1.9358x; 1.0407x over previous
//
#include <hip/hip_runtime.h>
#include <math.h>

// DigitCaps dynamic routing via MFMA u_hat + fused in-register routing.
// R4: 1152 small blocks (256 thr), unroll-2 ILP, NIC=36.
#define J 10
#define BT 16          // batch tile (MFMA N)
#define NBT 32         // BATCH/BT
#define NIC 36         // i-chunks
#define ICB 32         // IN_CAPS/NIC
#define IPW 8          // i per wave (4 waves/block)
#define JD 160
#define BATCH 512
#define IN_CAPS 1152
#define RTH 256

typedef __attribute__((ext_vector_type(8))) short short8;
typedef __attribute__((ext_vector_type(4))) float f32x4;

__device__ inline short f2bf(float f) {
    union { float f; unsigned u; } v; v.f = f;
    return (short)((v.u + 0x7FFFu + ((v.u >> 16) & 1u)) >> 16);  // RNE
}
__device__ inline short8 cvt8(float4 a, float4 b) {
    short8 o;
    o[0] = f2bf(a.x); o[1] = f2bf(a.y); o[2] = f2bf(a.z); o[3] = f2bf(a.w);
    o[4] = f2bf(b.x); o[5] = f2bf(b.y); o[6] = f2bf(b.z); o[7] = f2bf(b.w);
    return o;
}

// W fp32 -> bf16 (same [i][j][d][e] layout), and zero pad-buffer.
__global__ __launch_bounds__(256) void convert_kernel(
    const float* __restrict__ W, short* __restrict__ Wb, short* __restrict__ zb)
{
    const int t = blockIdx.x * 256 + threadIdx.x;   // 184320 threads exactly
    const float4* src = (const float4*)W + (size_t)t * 2;
    *(short8*)(Wb + (size_t)t * 8) = cvt8(src[0], src[1]);
    if (blockIdx.x == 0 && threadIdx.x < 32) zb[threadIdx.x] = 0;
}

// MFMA orientation: A = W (M rows = 16 d of one j), B = X (N cols = 16 b), K = e.
// C layout: col = lane&15 = b, row = (lane>>4)*4 + reg = d.
// MODE 0: c = 0.1 (pure GEMM, K=32 = 4 i x 8 e).  MODE 1: logits from V, softmax, s.
template<int MODE>
__global__ __launch_bounds__(RTH, 3) void route_kernel(
    const float* __restrict__ X, const short* __restrict__ Wb,
    const short* __restrict__ zb, const float* __restrict__ V,
    float* __restrict__ S_part)
{
    __shared__ float s_lds[BT][JD + 1];
    const int tid   = threadIdx.x;
    const int lane  = tid & 63, wave = tid >> 6;
    const int btile = blockIdx.x / NIC, icb = blockIdx.x % NIC;
    const int bcol  = lane & 15, kg = lane >> 4;

    for (int t = tid; t < BT * (JD + 1); t += RTH) (&s_lds[0][0])[t] = 0.f;
    __syncthreads();

    const int i0w = icb * ICB + wave * IPW;
    const int b   = btile * BT + bcol;

    if (MODE == 0) {
        f32x4 acc[J];
#pragma unroll
        for (int j = 0; j < J; ++j) acc[j] = (f32x4)(0.f);
#pragma unroll
        for (int st = 0; st < IPW / 4; ++st) {
            const int ia = i0w + st * 4 + kg;            // lane's i (k-group)
            const float4* xp = (const float4*)(X + ((size_t)b * IN_CAPS + ia) * 8);
            const short8 bfr = cvt8(xp[0], xp[1]);       // B = x[b, i(kg), e]
#pragma unroll
            for (int j = 0; j < J; ++j) {
                const short8 afr = *(const short8*)(Wb + ((size_t)ia * JD + j * 16 + bcol) * 8);
                acc[j] = __builtin_amdgcn_mfma_f32_16x16x32_bf16(afr, bfr, acc[j], 0, 0, 0);
            }
        }
#pragma unroll
        for (int j = 0; j < J; ++j)
#pragma unroll
            for (int r = 0; r < 4; ++r)
                atomicAdd(&s_lds[bcol][j * 16 + kg * 4 + r], 0.1f * acc[j][r]);
    } else {
        float Vr[J][4];
#pragma unroll
        for (int j = 0; j < J; ++j)
#pragma unroll
            for (int r = 0; r < 4; ++r)
                Vr[j][r] = V[(size_t)b * JD + j * 16 + kg * 4 + r];

        float s_acc[J][4];
#pragma unroll
        for (int j = 0; j < J; ++j)
#pragma unroll
            for (int r = 0; r < 4; ++r) s_acc[j][r] = 0.f;

        // zero-stride trick: lanes >=16 read the 64B zero buffer (k=8..31 pad).
        const bool act = (lane < 16);
        const float* xbase = act ? (X + (size_t)b * IN_CAPS * 8) : (const float*)zb;
        const int xis = act ? 8 : 0;
        const short* wb0 = act ? (Wb + (size_t)bcol * 8) : zb;
        const int wis = act ? (JD * 8) : 0;
        const int wjs = act ? 128 : 0;

#pragma unroll 2
        for (int ii = 0; ii < IPW; ++ii) {
            const int i = i0w + ii;
            const float4* xp = (const float4*)(xbase + (size_t)i * xis);
            const short8 bfr = cvt8(xp[0], xp[1]);
            const short* wp = wb0 + (size_t)i * wis;
            f32x4 u[J];
#pragma unroll
            for (int j = 0; j < J; ++j) {
                const short8 afr = *(const short8*)(wp + j * wjs);
                u[j] = __builtin_amdgcn_mfma_f32_16x16x32_bf16(afr, bfr, (f32x4)(0.f), 0, 0, 0);
            }
            // logits L[j] = sum_d u[d]*V[d]: 4 in-register + 2-step lane reduce
            float L[J];
#pragma unroll
            for (int j = 0; j < J; ++j) {
                float l = u[j][0] * Vr[j][0] + u[j][1] * Vr[j][1]
                        + u[j][2] * Vr[j][2] + u[j][3] * Vr[j][3];
                l += __shfl_xor(l, 16);
                l += __shfl_xor(l, 32);
                L[j] = l;
            }
            // softmax over j (logits bounded: |L| small, no max-sub needed)
            float e[J], Z = 0.f;
#pragma unroll
            for (int j = 0; j < J; ++j) { e[j] = __expf(L[j]); Z += e[j]; }
            const float rz = 1.0f / Z;
#pragma unroll
            for (int j = 0; j < J; ++j) {
                const float c = e[j] * rz;
#pragma unroll
                for (int r = 0; r < 4; ++r) s_acc[j][r] += c * u[j][r];
            }
        }
#pragma unroll
        for (int j = 0; j < J; ++j)
#pragma unroll
            for (int r = 0; r < 4; ++r)
                atomicAdd(&s_lds[bcol][j * 16 + kg * 4 + r], s_acc[j][r]);
    }
    __syncthreads();

    for (int t = tid; t < BT * JD; t += RTH) {
        const int bb = t / JD, p = t % JD;
        S_part[((size_t)icb * BATCH + btile * BT + bb) * JD + p] = s_lds[bb][p];
    }
}

// mode: 0 -> V = v, 1 -> V += v, 2 -> out = v
__global__ __launch_bounds__(256) void squash_kernel(
    const float* __restrict__ S_part, float* __restrict__ V,
    float* __restrict__ out, int mode)
{
    const int t = blockIdx.x * 256 + threadIdx.x;  // BATCH*JD threads
    float s = 0.f;
#pragma unroll
    for (int ic = 0; ic < NIC; ic++)
        s += S_part[(size_t)ic * BATCH * JD + t];
    float sq = s * s;
    sq += __shfl_xor(sq, 1);
    sq += __shfl_xor(sq, 2);
    sq += __shfl_xor(sq, 4);
    sq += __shfl_xor(sq, 8);
    const float v = s * sq / ((1.f + sq) * sqrtf(sq + 1e-8f));
    if (mode == 0)      V[t] = v;
    else if (mode == 1) V[t] += v;
    else                out[t] = v;
}

extern "C" void kernel_launch(void* const* d_in, const int* in_sizes, int n_in,
                              void* d_out, int out_size, void* d_ws, size_t ws_size,
                              hipStream_t stream)
{
    const float* X = (const float*)d_in[0];   // [512][1152][8]
    const float* W = (const float*)d_in[1];   // [1152][10][16][8]
    float* out = (float*)d_out;               // [512][10][16]

    // ws: S_part[36][512][160] f32 | V[512][160] f32 | Wb bf16 | zb (64B zeros)
    float* S_part = (float*)d_ws;
    float* V      = S_part + (size_t)NIC * BATCH * JD;
    short* Wb     = (short*)(V + (size_t)BATCH * JD);
    short* zb     = Wb + (size_t)IN_CAPS * JD * 8;

    const dim3 rg(NBT * NIC), rb(RTH);        // 1152 blocks x 4 waves
    const dim3 sg(BATCH * JD / 256), sb(256); // 320 blocks
    convert_kernel<<<dim3(IN_CAPS * JD * 8 / 2048), dim3(256), 0, stream>>>(W, Wb, zb);

    route_kernel<0><<<rg, rb, 0, stream>>>(X, Wb, zb, V, S_part);
    squash_kernel<<<sg, sb, 0, stream>>>(S_part, V, out, 0);   // V = v0
    route_kernel<1><<<rg, rb, 0, stream>>>(X, Wb, zb, V, S_part);
    squash_kernel<<<sg, sb, 0, stream>>>(S_part, V, out, 1);   // V += v1
    route_kernel<1><<<rg, rb, 0, stream>>>(X, Wb, zb, V, S_part);
    squash_kernel<<<sg, sb, 0, stream>>>(S_part, V, out, 2);   // out = v2
}